// Round 3
// baseline (236.865 us; speedup 1.0000x reference)
//
#include <hip/hip_runtime.h>

typedef unsigned short u16;
typedef __attribute__((ext_vector_type(4))) unsigned int u32x4;
typedef __attribute__((ext_vector_type(4))) float f32x4;
typedef __attribute__((ext_vector_type(8))) __bf16 bf16x8;

// Problem constants (fixed by the reference).
constexpr int BATCH = 2;
constexpr int NV    = 20000;
constexpr int ND    = 8;
constexpr int CH    = 16;
constexpr int NF    = 16;
constexpr int K0    = 1024;           // conv contraction (8 rings * 8 dirs * 16 ch)
constexpr int KE    = 1152;           // + center-kernel folded in (8 dirs * 16 ch)
constexpr int NCHUNK = KE / 32;       // 36 K-chunks of 32
constexpr int MTOT  = BATCH * NV;     // 40000 GEMM rows
constexpr int BSTR  = 40;             // padded B row stride in bf16 (32+8)

// ws layout (bytes):
//   [0, 10,240,000)              y16i : bf16 [NV*8 rows][BATCH][CH]  (batch-interleaved!)
//   [10,240,000, 10,534,912)     k2c  : bf16 [36][128][32]  (chunk-major weights)
//   [10,534,912, 102,694,912)    zc   : bf16 [36][40000][32] (chunk-major A matrix)
constexpr size_t Y16_OFF_B = 0;
constexpr size_t K2C_OFF_B = 10240000;
constexpr size_t ZC_OFF_B  = 10534912;   // total ws needed = 102,694,912 B

__device__ __forceinline__ u16 f2bf(float x) {
    unsigned int u = __float_as_uint(x);
    unsigned int r = (u + 0x7fffu + ((u >> 16) & 1u)) >> 16;   // RNE
    return (u16)r;
}
__device__ __forceinline__ unsigned int pack2bf(float a, float b) {
    return (unsigned int)f2bf(a) | ((unsigned int)f2bf(b) << 16);
}

// ---------------- P1: prep — y fp32 -> batch-interleaved y16i AND center chunks of zc ----
// one thread per (b,v,d): tid = b*160000 + v*8 + d.
__global__ __launch_bounds__(256) void prep(const float* __restrict__ y,
                                            u16* __restrict__ y16i,
                                            u16* __restrict__ zc) {
    int tid = blockIdx.x * 256 + threadIdx.x;       // [0, 320000)
    int b = tid >= 160000;
    int vd = tid - b * 160000;                      // v*8 + d
    const float4* src = (const float4*)(y + (size_t)tid * 16);
    float4 v0 = src[0], v1 = src[1], v2 = src[2], v3 = src[3];
    u32x4 lo = {pack2bf(v0.x, v0.y), pack2bf(v0.z, v0.w), pack2bf(v1.x, v1.y), pack2bf(v1.z, v1.w)};
    u32x4 hi = {pack2bf(v2.x, v2.y), pack2bf(v2.z, v2.w), pack2bf(v3.x, v3.y), pack2bf(v3.z, v3.w)};
    u16* yd = y16i + ((size_t)vd * 2 + b) * 16;     // 32 B slot inside the 64 B row-pair line
    *(u32x4*)(yd)     = lo;
    *(u32x4*)(yd + 8) = hi;
    int v = vd >> 3, d = vd & 7;
    int iv = b * NV + v;                            // GEMM row m
    u16* zd = zc + ((size_t)(32 + (d >> 1)) * MTOT + iv) * 32 + (d & 1) * 16;
    *(u32x4*)(zd)     = lo;
    *(u32x4*)(zd + 8) = hi;
}

// ---------------- P2: build rotated+extended weight matrix K2c ----------------
// K2c[kc][n][kk] = K2[k=kc*32+kk][n=w*16+f];  K2[(r,dd,c),(w,f)] = kernel[r,(dd-w)&7,c,f];
// ext rows (k>=1024, ke=d*16+c): (d==w) ? ck[c,f] : 0
__global__ __launch_bounds__(256) void k2_build(const float* __restrict__ kern,
                                                const float* __restrict__ ck,
                                                u16* __restrict__ k2c) {
    int e = blockIdx.x * 256 + threadIdx.x;   // [0, 36*4096)
    int i = e & 4095;
    int kc = e >> 12;
    int n = i >> 5, kk = i & 31;
    int k = kc * 32 + kk;
    int w = n >> 4, f = n & 15;
    float val;
    if (k < K0) {
        int r = k >> 7, dd = (k >> 4) & 7, c = k & 15;
        int d = (dd - w) & 7;
        val = kern[((r * 8 + d) * 16 + c) * 16 + f];
    } else {
        int ke = k - K0;
        int d = ke >> 4, c = ke & 15;
        val = (d == w) ? ck[c * 16 + f] : 0.f;
    }
    k2c[e] = f2bf(val);
}

// ---------------- G: gather + barycentric combine -> zc chunks 0..31, BOTH batches ------
// one thread per (v,rd): meta read once; each gather touches one full 64 B line
// (both batches of the (cn,an) row). Meta loads are non-temporal (read-once stream)
// so they don't evict the y16i table from L2/L3.
__global__ __launch_bounds__(256) void gather(const u16* __restrict__ y16i,
                                              const int* __restrict__ contrib,
                                              const float* __restrict__ wbary,
                                              const int* __restrict__ angles,
                                              u16* __restrict__ zc) {
    int item = blockIdx.x * 256 + threadIdx.x;     // [0, 1,280,000)
    int v = item >> 6, rd = item & 63;
    size_t mb = ((size_t)v * 64 + rd) * 3;

    float a0[CH], a1[CH];
    #pragma unroll
    for (int c = 0; c < CH; ++c) { a0[c] = 0.f; a1[c] = 0.f; }
    #pragma unroll
    for (int j = 0; j < 3; ++j) {
        int cn   = __builtin_nontemporal_load(contrib + mb + j);
        int an   = __builtin_nontemporal_load(angles + mb + j);
        float wj = __builtin_nontemporal_load(wbary + mb + j);
        const u32x4* src = (const u32x4*)(y16i + ((size_t)(cn * ND + an)) * 32);
        u32x4 p0 = src[0], p1 = src[1];   // batch 0 (32 B)
        u32x4 p2 = src[2], p3 = src[3];   // batch 1 (32 B)
        #pragma unroll
        for (int q = 0; q < 4; ++q) {
            unsigned int u = p0[q];
            a0[2 * q]     += wj * __uint_as_float(u << 16);
            a0[2 * q + 1] += wj * __uint_as_float(u & 0xffff0000u);
        }
        #pragma unroll
        for (int q = 0; q < 4; ++q) {
            unsigned int u = p1[q];
            a0[8 + 2 * q]     += wj * __uint_as_float(u << 16);
            a0[8 + 2 * q + 1] += wj * __uint_as_float(u & 0xffff0000u);
        }
        #pragma unroll
        for (int q = 0; q < 4; ++q) {
            unsigned int u = p2[q];
            a1[2 * q]     += wj * __uint_as_float(u << 16);
            a1[2 * q + 1] += wj * __uint_as_float(u & 0xffff0000u);
        }
        #pragma unroll
        for (int q = 0; q < 4; ++q) {
            unsigned int u = p3[q];
            a1[8 + 2 * q]     += wj * __uint_as_float(u << 16);
            a1[8 + 2 * q + 1] += wj * __uint_as_float(u & 0xffff0000u);
        }
    }
    u32x4 o0, o1, o2, o3;
    #pragma unroll
    for (int q = 0; q < 4; ++q) {
        o0[q] = pack2bf(a0[2 * q], a0[2 * q + 1]);
        o1[q] = pack2bf(a0[8 + 2 * q], a0[8 + 2 * q + 1]);
        o2[q] = pack2bf(a1[2 * q], a1[2 * q + 1]);
        o3[q] = pack2bf(a1[8 + 2 * q], a1[8 + 2 * q + 1]);
    }
    size_t zoff = ((size_t)(rd >> 1) * MTOT) * 32 + (size_t)(rd & 1) * 16;
    u16* d0 = zc + zoff + (size_t)v * 32;            // batch 0 row m=v
    u16* d1 = zc + zoff + (size_t)(v + NV) * 32;     // batch 1 row m=v+NV
    *(u32x4*)(d0)     = o0;
    *(u32x4*)(d0 + 8) = o1;
    *(u32x4*)(d1)     = o2;
    *(u32x4*)(d1 + 8) = o3;
}

// ---------------- M: GEMM (40000 x 1152 x 128) + bias + relu + max over w ----------------
// 625 blocks x 256 threads (4 waves). Wave w: rows m0+w*16..+15, all 128 cols.
// A: direct global->register, 2-deep prefetch (chunk-major zc => each wave's fragment
// load is a contiguous coalesced 1 KB). B: 288 KB L2-resident k2c, double-buffered in
// LDS. Epilogue: lane's 8 nt accumulators are the 8 w-rotations of filter f=lane&15
// -> in-register max, one exclusive store per (row,f).
__global__ __launch_bounds__(256) void gemm_max(const u16* __restrict__ zc,
                                                const u16* __restrict__ k2c,
                                                const float* __restrict__ bias,
                                                float* __restrict__ out) {
    __shared__ __align__(16) u16 Bb[2][128 * BSTR];   // 20,480 B
    const int t = threadIdx.x;
    const int w = t >> 6, lane = t & 63;
    const int lrow = lane & 15, lq = lane >> 4;
    const int m0 = blockIdx.x * 64;
    const int arow = m0 + w * 16 + lrow;
    const u16* abase = zc + (size_t)arow * 32 + lq * 8;

    // B staging: thread t stages n = t>>1, half = t&1 (32 B).
    const int sn = t >> 1, sh = (t & 1) * 16;

    // prologue: stage B[0], prefetch A[0], A[1]
    {
        const u32x4* src = (const u32x4*)(k2c + (size_t)sn * 32 + sh);
        u32x4 b0 = src[0], b1 = src[1];
        u16* dst = &Bb[0][sn * BSTR + sh];
        *(u32x4*)(dst)     = b0;
        *(u32x4*)(dst + 8) = b1;
    }
    bf16x8 a_p0 = *(const bf16x8*)(abase);
    bf16x8 a_p1 = *(const bf16x8*)(abase + (size_t)1 * MTOT * 32);

    f32x4 acc[8];
    #pragma unroll
    for (int nt = 0; nt < 8; ++nt) acc[nt] = (f32x4){0.f, 0.f, 0.f, 0.f};

    for (int kc = 0; kc < NCHUNK; ++kc) {
        __syncthreads();                               // B[kc] visible; B[(kc+1)&1] free
        bf16x8 a = a_p0;
        a_p0 = a_p1;
        if (kc < NCHUNK - 2)
            a_p1 = *(const bf16x8*)(abase + (size_t)(kc + 2) * MTOT * 32);
        u32x4 bn0, bn1;
        if (kc < NCHUNK - 1) {
            const u32x4* src = (const u32x4*)(k2c + (size_t)(kc + 1) * 4096 + sn * 32 + sh);
            bn0 = src[0]; bn1 = src[1];
        }
        bf16x8 bf[8];
        #pragma unroll
        for (int nt = 0; nt < 8; ++nt)
            bf[nt] = *(const bf16x8*)(&Bb[kc & 1][(nt * 16 + lrow) * BSTR + lq * 8]);
        #pragma unroll
        for (int nt = 0; nt < 8; ++nt)
            acc[nt] = __builtin_amdgcn_mfma_f32_16x16x32_bf16(a, bf[nt], acc[nt], 0, 0, 0);
        if (kc < NCHUNK - 1) {
            u16* dst = &Bb[(kc + 1) & 1][sn * BSTR + sh];
            *(u32x4*)(dst)     = bn0;
            *(u32x4*)(dst + 8) = bn1;
        }
    }

    // epilogue: +bias, relu, max over w (= max over nt), exclusive store
    const float bb = bias[lrow];
    #pragma unroll
    for (int reg = 0; reg < 4; ++reg) {
        float m = 0.f;   // relu floor
        #pragma unroll
        for (int nt = 0; nt < 8; ++nt) m = fmaxf(m, acc[nt][reg] + bb);
        out[((size_t)(m0 + w * 16 + lq * 4 + reg)) * NF + lrow] = m;
    }
}

extern "C" void kernel_launch(void* const* d_in, const int* in_sizes, int n_in,
                              void* d_out, int out_size, void* d_ws, size_t ws_size,
                              hipStream_t stream) {
    const float* y      = (const float*)d_in[0];
    const int*   contrib= (const int*)d_in[1];
    const float* wbary  = (const float*)d_in[2];
    const int*   angles = (const int*)d_in[3];
    const float* kern   = (const float*)d_in[4];
    const float* ck     = (const float*)d_in[5];
    const float* bias   = (const float*)d_in[6];
    float* out = (float*)d_out;

    u16* y16i = (u16*)((char*)d_ws + Y16_OFF_B);
    u16* k2c  = (u16*)((char*)d_ws + K2C_OFF_B);
    u16* zc   = (u16*)((char*)d_ws + ZC_OFF_B);   // needs ws_size >= 102,694,912 B

    prep<<<1250, 256, 0, stream>>>(y, y16i, zc);                                  // y16i + zc chunks 32..35
    k2_build<<<(NCHUNK * 4096) / 256, 256, 0, stream>>>(kern, ck, k2c);           // 576 blocks
    gather<<<5000, 256, 0, stream>>>(y16i, contrib, wbary, angles, zc);           // zc chunks 0..31
    gemm_max<<<MTOT / 64, 256, 0, stream>>>(zc, k2c, bias, out);                  // 625 blocks
}